// Round 1
// 13928.586 us; speedup vs baseline: 1.0221x; 1.0221x over previous
//
#include <hip/hip_runtime.h>
#include <cmath>

// ---------------- problem constants ----------------
#define NB    16384
#define NT    7
#define ND    1024
#define NH    512
#define NE    64

// ---------------- workspace layout (float offsets) ----------------
#define OFF_WCAT   0ll            // 1536*2048 packed [k][n'] gate-interleaved
#define OFF_BLSTM  3145728ll      // 2048 interleaved bias
#define OFF_GW1P   3147776ll      // 1552*1024 (rows >=1540 zero)
#define OFF_FW1P   4737024ll      // 1024*512
#define OFF_GW2T   5261312ll      // 1024*64
#define OFF_H0     5326848ll      // 16384*512
#define OFF_H1     13715456ll     // 16384*512
#define OFF_C      22104064ll     // 16384*512
#define OFF_HID    30492672ll     // 16384*1024 (flow hidden aliases low half)
#define OFF_FLOW   47269888ll     // 16384*4
#define OFF_UACC   47335424ll     // 64
#define WS_FLOATS  47335488ll

// ---------------- output layout (float offsets in d_out) ----------------
#define OUT_TOPKP  0ll
#define OUT_IDX    131072ll
#define OUT_LOSS   262144ll
#define OUT_FLOW   262145ll
#define OUT_USAGE  327681ll
#define OUT_ADJ    327745ll

__device__ __forceinline__ float sigm(float x) { return 1.0f / (1.0f + expf(-x)); }

// async global -> LDS, 16B per lane. LDS dest must be wave-uniform base + lane*16.
__device__ __forceinline__ void gload_lds16(const float* __restrict__ g, float* s) {
  __builtin_amdgcn_global_load_lds((const __attribute__((address_space(1))) void*)g,
                                   (__attribute__((address_space(3))) void*)s, 16, 0, 0);
}

// ---------------- weight packing ----------------
__global__ void pack_lstm_k(const float* __restrict__ Wih, const float* __restrict__ Whh,
                            const float* __restrict__ bih, const float* __restrict__ bhh,
                            float* __restrict__ wcat, float* __restrict__ bl) {
  int idx = blockIdx.x * 256 + threadIdx.x;
  if (idx < 1536 * 2048) {
    int k = idx >> 11, n = idx & 2047;
    int u = n >> 2, g = n & 3;
    int r = g * 512 + u;
    wcat[idx] = (k < 1024) ? Wih[(size_t)r * 1024 + k] : Whh[(size_t)r * 512 + (k - 1024)];
  }
  if (idx < 2048) {
    int u = idx >> 2, g = idx & 3;
    int r = g * 512 + u;
    bl[idx] = bih[r] + bhh[r];
  }
}

__global__ void pack_gw1_k(const float* __restrict__ gw1, float* __restrict__ gw1p) {
  int idx = blockIdx.x * 256 + threadIdx.x;
  if (idx < 1552 * 1024) {
    int k = idx >> 10, n = idx & 1023;
    gw1p[idx] = (k < 1540) ? gw1[(size_t)n * 1540 + k] : 0.0f;
  }
}

__global__ void pack_fw1_k(const float* __restrict__ fw1, float* __restrict__ fw1p) {
  int idx = blockIdx.x * 256 + threadIdx.x;
  if (idx < 1024 * 512) {
    int k = idx >> 9, n = idx & 511;
    fw1p[idx] = fw1[(size_t)n * 1024 + k];
  }
}

__global__ void pack_gw2t_k(const float* __restrict__ gw2, float* __restrict__ gw2t) {
  int idx = blockIdx.x * 256 + threadIdx.x;
  if (idx < 1024 * 64) {
    int k = idx >> 6, e = idx & 63;
    gw2t[idx] = gw2[(size_t)e * 1024 + k];
  }
}

// ---------------- A-gather (up to 3 row segments, quad-aligned) ----------------
__device__ __forceinline__ float4 ldA4(const float* __restrict__ p0, int s0, int L0,
                                       const float* __restrict__ p1, int s1, int L01,
                                       const float* __restrict__ p2, int s2, int L012,
                                       int m, int k) {
  if (k < L0)   return *(const float4*)(p0 + (size_t)m * s0 + k);
  if (k < L01)  return *(const float4*)(p1 + (size_t)m * s1 + (k - L0));
  if (k < L012) return *(const float4*)(p2 + (size_t)m * s2 + (k - L01));
  return make_float4(0.f, 0.f, 0.f, 0.f);
}

// ---------------- 128x128x16 fp32 GEMM, double-buffered LDS ----------------
// B fragment per thread: cols {tx*4..+3} and {64+tx*4..+3}  (conflict-free reads:
// 16 distinct float4 addrs span all 32 banks at <=2-way, free on wave64).
// B staged via global_load_lds (linear LDS dest = wave base + lane*16).
// EPI=0: out = relu(acc + bias) stored to outp (ldo)
// EPI=1: LSTM gate epilogue (gate-interleaved columns), updates cbuf/hbuf
template <int EPI>
__global__ __launch_bounds__(256) void gemm128(
    const float* __restrict__ p0, int s0, int L0,
    const float* __restrict__ p1, int s1, int L01,
    const float* __restrict__ p2, int s2, int L012,
    const float* __restrict__ Bp, int N, int nk,
    const float* __restrict__ bias,
    float* __restrict__ outp, int ldo,
    float* __restrict__ cbuf, float* __restrict__ hbuf, int first) {
  __shared__ __align__(16) float As[2][16][132];
  __shared__ __align__(16) float Bs[2][16][128];   // stride 128: required linear for global_load_lds
  const int t = threadIdx.x;
  const int ntn = N >> 7;
  const int bn = blockIdx.x % ntn;
  const int bm = blockIdx.x / ntn;
  const int m0 = bm << 7, n0 = bn << 7;
  const int tx = t & 15, ty = t >> 4;
  const int lm = t & 127;
  const int kq = (t >> 7) << 3;
  const int lbk = t >> 5;
  const int lbn = (t & 31) << 2;
  const int am = m0 + lm;

  float acc[8][8];
#pragma unroll
  for (int i = 0; i < 8; i++)
#pragma unroll
    for (int j = 0; j < 8; j++) acc[i][j] = 0.f;

  // ---- prologue staging: B async -> LDS, A via regs (transposed store) ----
  gload_lds16(Bp + (size_t)lbk * N + n0 + lbn, &Bs[0][lbk][lbn]);
  gload_lds16(Bp + (size_t)(lbk + 8) * N + n0 + lbn, &Bs[0][lbk + 8][lbn]);
  float4 a0 = ldA4(p0, s0, L0, p1, s1, L01, p2, s2, L012, am, kq);
  float4 a1 = ldA4(p0, s0, L0, p1, s1, L01, p2, s2, L012, am, kq + 4);
  As[0][kq + 0][lm] = a0.x; As[0][kq + 1][lm] = a0.y;
  As[0][kq + 2][lm] = a0.z; As[0][kq + 3][lm] = a0.w;
  As[0][kq + 4][lm] = a1.x; As[0][kq + 5][lm] = a1.y;
  As[0][kq + 6][lm] = a1.z; As[0][kq + 7][lm] = a1.w;
  __syncthreads();   // drains vmcnt (B lds-writes) + lgkmcnt

  int cur = 0;
  for (int kt = 0; kt < nk; ++kt) {
    const bool more = (kt + 1 < nk);
    if (more) {
      const int kb = (kt + 1) << 4;
      // issue next B tile async into the other buffer (overlaps with compute below)
      gload_lds16(Bp + (size_t)(kb + lbk) * N + n0 + lbn, &Bs[cur ^ 1][lbk][lbn]);
      gload_lds16(Bp + (size_t)(kb + lbk + 8) * N + n0 + lbn, &Bs[cur ^ 1][lbk + 8][lbn]);
      a0 = ldA4(p0, s0, L0, p1, s1, L01, p2, s2, L012, am, kb + kq);
      a1 = ldA4(p0, s0, L0, p1, s1, L01, p2, s2, L012, am, kb + kq + 4);
    }
#pragma unroll
    for (int kk = 0; kk < 16; ++kk) {
      float4 av0 = *(const float4*)&As[cur][kk][ty << 3];
      float4 av1 = *(const float4*)&As[cur][kk][(ty << 3) + 4];
      float4 bv0 = *(const float4*)&Bs[cur][kk][tx << 2];
      float4 bv1 = *(const float4*)&Bs[cur][kk][64 + (tx << 2)];
      float ar[8] = {av0.x, av0.y, av0.z, av0.w, av1.x, av1.y, av1.z, av1.w};
      float br[8] = {bv0.x, bv0.y, bv0.z, bv0.w, bv1.x, bv1.y, bv1.z, bv1.w};
#pragma unroll
      for (int i = 0; i < 8; i++)
#pragma unroll
        for (int j = 0; j < 8; j++) acc[i][j] = fmaf(ar[i], br[j], acc[i][j]);
    }
    if (more) {
      const int nb2 = cur ^ 1;
      As[nb2][kq + 0][lm] = a0.x; As[nb2][kq + 1][lm] = a0.y;
      As[nb2][kq + 2][lm] = a0.z; As[nb2][kq + 3][lm] = a0.w;
      As[nb2][kq + 4][lm] = a1.x; As[nb2][kq + 5][lm] = a1.y;
      As[nb2][kq + 6][lm] = a1.z; As[nb2][kq + 7][lm] = a1.w;
      __syncthreads();   // also drains async B writes into nb2
      cur = nb2;
    }
  }

  // ---- epilogue: thread owns col quads c0 = n0+tx*4 and c0+64 ----
  const int c0 = n0 + (tx << 2);
  float ba[4], bb[4];
#pragma unroll
  for (int j = 0; j < 4; j++) { ba[j] = bias[c0 + j]; bb[j] = bias[c0 + 64 + j]; }

  if (EPI == 0) {
#pragma unroll
    for (int i = 0; i < 8; i++) {
      const int m = m0 + (ty << 3) + i;
      float4 o0, o1;
      o0.x = fmaxf(acc[i][0] + ba[0], 0.f);
      o0.y = fmaxf(acc[i][1] + ba[1], 0.f);
      o0.z = fmaxf(acc[i][2] + ba[2], 0.f);
      o0.w = fmaxf(acc[i][3] + ba[3], 0.f);
      o1.x = fmaxf(acc[i][4] + bb[0], 0.f);
      o1.y = fmaxf(acc[i][5] + bb[1], 0.f);
      o1.z = fmaxf(acc[i][6] + bb[2], 0.f);
      o1.w = fmaxf(acc[i][7] + bb[3], 0.f);
      *(float4*)(outp + (size_t)m * ldo + c0) = o0;
      *(float4*)(outp + (size_t)m * ldo + c0 + 64) = o1;
    }
  } else {
    // gate-interleaved: col = 4u+g -> unit ub+tx (p=0), ub+tx+16 (p=1), gate = j
    const int ub = (n0 >> 2) + tx;
#pragma unroll
    for (int i = 0; i < 8; i++) {
      const int m = m0 + (ty << 3) + i;
#pragma unroll
      for (int p = 0; p < 2; p++) {
        const float* bq = p ? bb : ba;
        const float ig = sigm(acc[i][4 * p + 0] + bq[0]);
        const float fg = sigm(acc[i][4 * p + 1] + bq[1]);
        const float gg = tanhf(acc[i][4 * p + 2] + bq[2]);
        const float og = sigm(acc[i][4 * p + 3] + bq[3]);
        const size_t off = (size_t)m * 512 + ub + 16 * p;
        const float cold = first ? 0.f : cbuf[off];
        const float cn = fg * cold + ig * gg;
        cbuf[off] = cn;
        hbuf[off] = og * tanhf(cn);
      }
    }
  }
}

// ---------------- flow head: 4 logits + softmax, wave per row ----------------
__global__ __launch_bounds__(256) void flow_head(
    const float* __restrict__ h1, const float* __restrict__ fw2,
    const float* __restrict__ fb2, float* __restrict__ fout,
    float* __restrict__ fws) {
  __shared__ float w[2048];
  const int t = threadIdx.x;
  for (int i = t; i < 2048; i += 256) w[i] = fw2[i];
  __syncthreads();
  const int wid = t >> 6, lane = t & 63;
  const int row = blockIdx.x * 4 + wid;
  const float* hr = h1 + (size_t)row * 512;
  float s0 = 0, s1 = 0, s2 = 0, s3 = 0;
#pragma unroll
  for (int j = 0; j < 8; j++) {
    const int k = j * 64 + lane;
    const float hv = hr[k];
    s0 = fmaf(hv, w[k], s0);
    s1 = fmaf(hv, w[512 + k], s1);
    s2 = fmaf(hv, w[1024 + k], s2);
    s3 = fmaf(hv, w[1536 + k], s3);
  }
  for (int off = 32; off; off >>= 1) {
    s0 += __shfl_xor(s0, off);
    s1 += __shfl_xor(s1, off);
    s2 += __shfl_xor(s2, off);
    s3 += __shfl_xor(s3, off);
  }
  const float l0 = s0 + fb2[0], l1 = s1 + fb2[1], l2 = s2 + fb2[2], l3 = s3 + fb2[3];
  const float mx = fmaxf(fmaxf(l0, l1), fmaxf(l2, l3));
  const float e0 = expf(l0 - mx), e1 = expf(l1 - mx), e2 = expf(l2 - mx), e3 = expf(l3 - mx);
  const float inv = 1.0f / (e0 + e1 + e2 + e3);
  if (lane < 4) {
    const float v = (lane == 0 ? e0 : lane == 1 ? e1 : lane == 2 ? e2 : e3) * inv;
    fout[(size_t)row * 4 + lane] = v;
    fws[(size_t)row * 4 + lane] = v;
  }
}

// ---------------- moe head: 64 logits, softmax, top-8, usage ----------------
__global__ __launch_bounds__(256) void moe_head(
    const float* __restrict__ hid, const float* __restrict__ gw2t,
    const float* __restrict__ gb2, const float* __restrict__ spec,
    const float* __restrict__ flow, float* __restrict__ dout,
    float* __restrict__ uacc) {
  __shared__ __align__(16) float bs[8192];
  __shared__ float pbuf[256];
  const int t = threadIdx.x;
  const int wid = t >> 6, lane = t & 63;
  const int row = blockIdx.x * 4 + wid;
  const float* hr = hid + (size_t)row * 1024;
  float acc = 0.f;
  for (int kc = 0; kc < 8; ++kc) {
    __syncthreads();
    const float* src = gw2t + (size_t)kc * 8192;
#pragma unroll
    for (int q = 0; q < 8; q++) {
      const int o = q * 1024 + t * 4;
      *(float4*)&bs[o] = *(const float4*)&src[o];
    }
    __syncthreads();
    const float h0 = hr[kc * 128 + lane];
    const float h1v = hr[kc * 128 + 64 + lane];
#pragma unroll
    for (int kk = 0; kk < 64; kk++) acc = fmaf(__shfl(h0, kk), bs[kk * 64 + lane], acc);
#pragma unroll
    for (int kk = 0; kk < 64; kk++) acc = fmaf(__shfl(h1v, kk), bs[(64 + kk) * 64 + lane], acc);
  }
  const int e = lane;
  const float f0 = flow[(size_t)row * 4 + 0], f1 = flow[(size_t)row * 4 + 1];
  const float f2 = flow[(size_t)row * 4 + 2], f3 = flow[(size_t)row * 4 + 3];
  const float sp = f0 * spec[e * 4 + 0] + f1 * spec[e * 4 + 1] +
                   f2 * spec[e * 4 + 2] + f3 * spec[e * 4 + 3];
  const float adj = acc + gb2[e] + 0.1f * sp;
  dout[OUT_ADJ + (size_t)row * 64 + e] = adj;
  // softmax over 64 lanes
  float mx = adj;
  for (int off = 32; off; off >>= 1) mx = fmaxf(mx, __shfl_xor(mx, off));
  const float pe = expf(adj - mx);
  float ssum = pe;
  for (int off = 32; off; off >>= 1) ssum += __shfl_xor(ssum, off);
  const float prob = pe / ssum;
  pbuf[wid * 64 + e] = prob;
  // top-8 (ties -> lowest index, matching jax.lax.top_k)
  float v = prob;
  float selv = 0.f;
  int seli = 0;
  float s8 = 0.f;
#pragma unroll
  for (int it = 0; it < 8; ++it) {
    float bvv = v;
    int bi = e;
    for (int off = 32; off; off >>= 1) {
      const float ov = __shfl_xor(bvv, off);
      const int oi = __shfl_xor(bi, off);
      if (ov > bvv || (ov == bvv && oi < bi)) { bvv = ov; bi = oi; }
    }
    s8 += bvv;
    if (lane == it) { selv = bvv; seli = bi; }
    if (e == bi) v = -1.0f;
  }
  if (lane < 8) {
    dout[OUT_TOPKP + (size_t)row * 8 + lane] = selv / (s8 + 1e-8f);
    dout[OUT_IDX + (size_t)row * 8 + lane] = (float)seli;
  }
  __syncthreads();
  if (t < 64) {
    const float u = pbuf[t] + pbuf[64 + t] + pbuf[128 + t] + pbuf[192 + t];
    atomicAdd(&uacc[t], u);
  }
}

// ---------------- finalize: expert_usage + KL loss ----------------
__global__ void finalize_k(const float* __restrict__ uacc, float* __restrict__ dout) {
  const int e = threadIdx.x;  // 64 threads = 1 wave
  const float u = uacc[e] * (1.0f / 16384.0f);
  dout[OUT_USAGE + e] = u;
  float term = (logf(1.0f / 64.0f) - logf(u)) * (1.0f / 64.0f);
  for (int off = 32; off; off >>= 1) term += __shfl_xor(term, off);
  if (e == 0) dout[OUT_LOSS] = term * (1.0f / 64.0f);
}

// ---------------- host ----------------
extern "C" void kernel_launch(void* const* d_in, const int* in_sizes, int n_in,
                              void* d_out, int out_size, void* d_ws, size_t ws_size,
                              hipStream_t stream) {
  (void)in_sizes; (void)n_in; (void)out_size;
  if (ws_size < (size_t)WS_FLOATS * 4) return;

  const float* x    = (const float*)d_in[0];
  const float* ctx  = (const float*)d_in[1];
  const float* Wih  = (const float*)d_in[2];
  const float* Whh  = (const float*)d_in[3];
  const float* bih  = (const float*)d_in[4];
  const float* bhh  = (const float*)d_in[5];
  const float* fw1  = (const float*)d_in[6];
  const float* fb1  = (const float*)d_in[7];
  const float* fw2  = (const float*)d_in[8];
  const float* fb2  = (const float*)d_in[9];
  const float* gw1  = (const float*)d_in[10];
  const float* gb1  = (const float*)d_in[11];
  const float* gw2  = (const float*)d_in[12];
  const float* gb2  = (const float*)d_in[13];
  const float* spec = (const float*)d_in[14];
  float* out = (float*)d_out;
  float* ws = (float*)d_ws;

  float* wcat = ws + OFF_WCAT;
  float* bl   = ws + OFF_BLSTM;
  float* gw1p = ws + OFF_GW1P;
  float* fw1p = ws + OFF_FW1P;
  float* gw2t = ws + OFF_GW2T;
  float* H0   = ws + OFF_H0;
  float* H1   = ws + OFF_H1;
  float* C    = ws + OFF_C;
  float* HID  = ws + OFF_HID;
  float* FLW  = ws + OFF_FLOW;
  float* UA   = ws + OFF_UACC;

  hipMemsetAsync(UA, 0, 64 * sizeof(float), stream);
  pack_lstm_k<<<12288, 256, 0, stream>>>(Wih, Whh, bih, bhh, wcat, bl);
  pack_gw1_k<<<6208, 256, 0, stream>>>(gw1, gw1p);
  pack_fw1_k<<<2048, 256, 0, stream>>>(fw1, fw1p);
  pack_gw2t_k<<<256, 256, 0, stream>>>(gw2, gw2t);

  // flow layer 1: h1 = relu(x @ fw1^T + fb1) -> HID (low half, reused later)
  gemm128<0><<<128 * 4, 256, 0, stream>>>(x, 1024, 1024, x, 0, 1024, x, 0, 1024,
                                          fw1p, 512, 64, fb1, HID, 512,
                                          nullptr, nullptr, 0);
  flow_head<<<4096, 256, 0, stream>>>(HID, fw2, fb2, out + OUT_FLOW, FLW);

  // LSTM: 7 fused steps, h ping-pong (t even writes H0)
  for (int t = 0; t < 7; t++) {
    float* hout = (t & 1) ? H1 : H0;
    float* hin  = (t & 1) ? H0 : H1;
    const int K = t ? 1536 : 1024;
    gemm128<1><<<128 * 16, 256, 0, stream>>>(ctx + (size_t)t * 1024, 7168, 1024,
                                             hin, 512, K, hin, 0, K,
                                             wcat, 2048, K >> 4, bl, nullptr, 0,
                                             C, hout, t == 0 ? 1 : 0);
  }

  // main gate layer 1: hidden = relu([x|h|flow] @ gw1^T + gb1)
  gemm128<0><<<128 * 8, 256, 0, stream>>>(x, 1024, 1024, H0, 512, 1536,
                                          FLW, 4, 1540, gw1p, 1024, 97, gb1,
                                          HID, 1024, nullptr, nullptr, 0);

  moe_head<<<4096, 256, 0, stream>>>(HID, gw2t, gb2, spec, FLW, out, UA);
  finalize_k<<<1, 64, 0, stream>>>(UA, out);
}